// Round 1
// baseline (3435.592 us; speedup 1.0000x reference)
//
#include <hip/hip_runtime.h>

#define B_   64
#define T_   512
#define D_   512
#define H_   1024
#define G4   4096      // 4*H
#define KTOT 1536      // D + H
#define KC_N 48        // KTOT / 32
#define AP   1544      // padded LDS A-row stride (1536 + 8): breaks 32-bank aliasing

typedef float f32x4 __attribute__((ext_vector_type(4)));
typedef short s16x8 __attribute__((ext_vector_type(8)));

__device__ __forceinline__ unsigned short f2bf(float f) {
    unsigned int u = __float_as_uint(f);
    u = (u + 0x7fffu + ((u >> 16) & 1u)) >> 16;   // RNE
    return (unsigned short)u;
}
__device__ __forceinline__ float bf2f(unsigned short h) {
    return __uint_as_float(((unsigned int)h) << 16);
}
__device__ __forceinline__ float sigm(float x) { return 1.f / (1.f + __expf(-x)); }
__device__ __forceinline__ float tanh_f(float x) { return 1.f - 2.f / (__expf(2.f * x) + 1.f); }

// Pack [W_ih | W_hh] into exact MFMA B-fragment order, bf16, with gate-interleaved
// columns: packed col n = 4*j_hidden + gate  (so one block owns all 4 gates of a j).
// Layout: Wpk[(((c*48 + kc)*64 + lane))*8 + j] = W[row(n)][k], n = c*16 + (lane&15),
// k = kc*32 + (lane>>4)*8 + j.  => per-wave b-frag load is one coalesced dwordx4.
__global__ __launch_bounds__(256) void pack_w(const float* __restrict__ W_ih,
                                              const float* __restrict__ W_hh,
                                              unsigned short* __restrict__ Wpk) {
    int tid = blockIdx.x * 256 + threadIdx.x;        // [0, 256*48*64*8)
    int j    = tid & 7;
    int lane = (tid >> 3) & 63;
    int rest = tid >> 9;
    int kc = rest % KC_N;
    int c  = rest / KC_N;
    int npk = c * 16 + (lane & 15);
    int jh = npk >> 2, g = npk & 3;
    int row = g * H_ + jh;                           // torch gate order i,f,g,o
    int k = kc * 32 + (lane >> 4) * 8 + j;
    float v = (k < D_) ? W_ih[row * D_ + k] : W_hh[row * H_ + (k - D_)];
    Wpk[tid] = f2bf(v);
}

__global__ __launch_bounds__(256) void init_state(const float* __restrict__ h0,
                                                  const float* __restrict__ c0,
                                                  const float* __restrict__ b_ih,
                                                  const float* __restrict__ b_hh,
                                                  unsigned short* __restrict__ h_a,
                                                  float* __restrict__ c_cur,
                                                  float* __restrict__ bias_p) {
    int tid = blockIdx.x * 256 + threadIdx.x;        // 65536
    int j = tid & (H_ - 1);
    h_a[tid]  = f2bf(h0[j]);
    c_cur[tid] = c0[j];
    if (tid < G4) {                                  // bias in packed-col order
        int jh = tid >> 2, g = tid & 3;
        bias_p[tid] = b_ih[g * H_ + jh] + b_hh[g * H_ + jh];
    }
}

// One timestep: gates = [x_t | h] (16x1536) x Wpk-slice (1536x64 packed cols),
// then fused LSTM cell update. Grid (64 gate-blocks, 4 batch-blocks), 256 thr.
__global__ __launch_bounds__(256) void lstm_step(
    const float* __restrict__ x, const int* __restrict__ mask,
    const unsigned short* __restrict__ Wpk, const float* __restrict__ bias_p,
    const unsigned short* __restrict__ h_in, unsigned short* __restrict__ h_out,
    float* __restrict__ c_cur, float* __restrict__ out, int t)
{
    __shared__ unsigned short At[16 * AP];   // [x_t | h] tile, bf16, padded rows
    __shared__ float Dl[16][66];             // gates f32, padded

    const int tid = threadIdx.x;
    const int b0 = blockIdx.y * 16;
    const int bx = blockIdx.x;

    // ---- stage x_t slice (fp32 -> bf16), rows = batch ----
    #pragma unroll
    for (int i = 0; i < 8; ++i) {
        int e = i * 256 + tid;               // [0, 2048): 16 rows x 128 float4
        int r = e >> 7, c4 = e & 127;
        float4 v = *reinterpret_cast<const float4*>(x + ((b0 + r) * T_ + t) * D_ + c4 * 4);
        unsigned int lo = ((unsigned int)f2bf(v.y) << 16) | f2bf(v.x);
        unsigned int hi = ((unsigned int)f2bf(v.w) << 16) | f2bf(v.z);
        *reinterpret_cast<uint2*>(&At[r * AP + c4 * 4]) = make_uint2(lo, hi);
    }
    // ---- stage h slice (bf16 copy) ----
    #pragma unroll
    for (int i = 0; i < 8; ++i) {
        int e = i * 256 + tid;               // [0, 2048): 16 rows x 128 chunks of 8
        int r = e >> 7, c8 = e & 127;
        uint4 v = *reinterpret_cast<const uint4*>(h_in + (b0 + r) * H_ + c8 * 8);
        *reinterpret_cast<uint4*>(&At[r * AP + D_ + c8 * 8]) = v;
    }
    __syncthreads();

    // ---- MFMA: wave w computes 16 batch x 16 packed-gate-cols ----
    const int w = tid >> 6, l = tid & 63;
    const int quad = l >> 4, l15 = l & 15;
    const int cgrp = bx * 4 + w;             // global 16-col group [0,256)

    f32x4 acc = {0.f, 0.f, 0.f, 0.f};
    const unsigned short* atp = &At[l15 * AP + quad * 8];          // A[m=lane&15][k=quad*8+j]
    const unsigned short* bp  = Wpk + ((size_t)(cgrp * KC_N) * 64 + l) * 8;
    #pragma unroll 4
    for (int kc = 0; kc < KC_N; ++kc) {
        s16x8 af = *reinterpret_cast<const s16x8*>(atp + kc * 32);
        s16x8 bf = *reinterpret_cast<const s16x8*>(bp + kc * 64 * 8);
        acc = __builtin_amdgcn_mfma_f32_16x16x32_bf16(af, bf, acc, 0, 0, 0);
    }
    // C/D layout: col = lane&15, row = quad*4 + reg  (m89-verified)
    #pragma unroll
    for (int r = 0; r < 4; ++r)
        Dl[quad * 4 + r][w * 16 + l15] = acc[r];
    __syncthreads();

    // ---- epilogue: thread -> (batch b, hidden u); 4 gates are cols 4u..4u+3 ----
    const int b = tid >> 4, u = tid & 15;
    const int jh = bx * 16 + u;
    float4 bias = *reinterpret_cast<const float4*>(bias_p + bx * 64 + u * 4);
    float gi = sigm (Dl[b][u * 4 + 0] + bias.x);
    float gf = sigm (Dl[b][u * 4 + 1] + bias.y);
    float gg = tanh_f(Dl[b][u * 4 + 2] + bias.z);
    float go = sigm (Dl[b][u * 4 + 3] + bias.w);

    const int sidx = (b0 + b) * H_ + jh;
    float c_old = c_cur[sidx];
    float h_old = bf2f(At[b * AP + D_ + jh]);      // previous h from LDS stage
    float c_new = gf * c_old + gi * gg;
    float h_new = go * tanh_f(c_new);
    int m = mask[(b0 + b) * T_ + t];
    float h2 = m ? h_new : h_old;
    float c2 = m ? c_new : c_old;
    c_cur[sidx] = c2;
    h_out[sidx] = f2bf(h2);                        // always write: next step reads h_out
    out[((size_t)(b0 + b) * T_ + t) * H_ + jh] = h2;
}

extern "C" void kernel_launch(void* const* d_in, const int* in_sizes, int n_in,
                              void* d_out, int out_size, void* d_ws, size_t ws_size,
                              hipStream_t stream)
{
    const float* x    = (const float*)d_in[0];
    const int*   mask = (const int*)d_in[1];
    const float* W_ih = (const float*)d_in[2];
    const float* W_hh = (const float*)d_in[3];
    const float* b_ih = (const float*)d_in[4];
    const float* b_hh = (const float*)d_in[5];
    const float* h0   = (const float*)d_in[6];
    const float* c0   = (const float*)d_in[7];
    float* out = (float*)d_out;

    // ws layout (~13 MB total)
    char* wsb = (char*)d_ws;
    unsigned short* Wpk    = (unsigned short*)(wsb);             // 12,582,912 B
    float*          bias_p = (float*)(wsb + 12582912);           //     16,384 B
    unsigned short* h_a    = (unsigned short*)(wsb + 12599296);  //    131,072 B
    unsigned short* h_b    = (unsigned short*)(wsb + 12730368);  //    131,072 B
    float*          c_cur  = (float*)(wsb + 12861440);           //    262,144 B

    // re-poisoned every call -> re-pack every call (one-time cost ~50-100 us)
    pack_w<<<24576, 256, 0, stream>>>(W_ih, W_hh, Wpk);
    init_state<<<256, 256, 0, stream>>>(h0, c0, b_ih, b_hh, h_a, c_cur, bias_p);

    dim3 grid(64, 4);
    for (int t = 0; t < T_; ++t) {
        const unsigned short* hin = (t & 1) ? h_b : h_a;
        unsigned short*      hout = (t & 1) ? h_a : h_b;
        lstm_step<<<grid, 256, 0, stream>>>(x, mask, Wpk, bias_p, hin, hout, c_cur, out, t);
    }
}